// Round 20
// baseline (61.112 us; speedup 1.0000x reference)
//
#include <hip/hip_runtime.h>

// ---------------------------------------------------------------------------
// AttentionHead: GroupNorm -> QKV 1x1 conv -> softmax attention -> 1x1 conv.
// Round 20: 3 dispatches. attn redesigned: each of 4 waves owns a PRIVATE
// K/V LDS stream (m-quarter, dual-subtile r16 body) -> ZERO block barriers in
// the main loop (per-wave s_waitcnt vmcnt(0) instead of __syncthreads drain
// convoys). Block owns full softmax rows for 64 n-cols -> f32 LDS merge of
// the 4 quarters, normalize, and the output projection runs IN-BLOCK
// (out_proj dispatch, Opart, Lpart all eliminated).
// gn_stats / gn_qkv byte-identical to r19-verified.
// ---------------------------------------------------------------------------

#define B_ 4
#define C_ 64
#define D_ 64
#define N_ 4096

using bf16x8 = __attribute__((ext_vector_type(8))) short;     // 8 bf16 = 4 VGPR
using u16x8  = __attribute__((ext_vector_type(8))) unsigned short;
using u32x4  = __attribute__((ext_vector_type(4))) unsigned int;
using f32x16 = __attribute__((ext_vector_type(16))) float;

// round-to-nearest-even f32 -> bf16 bits
__device__ __forceinline__ unsigned short f2bf(float f) {
    unsigned u = __builtin_bit_cast(unsigned, f);
    u = (u + 0x7FFFu + ((u >> 16) & 1u)) >> 16;
    return (unsigned short)u;
}

// single-instruction exp2: builtin (backend-hazard-managed) or asm + s_nop
#if __has_builtin(__builtin_amdgcn_exp2f)
__device__ __forceinline__ float fast_exp2(float x) {
    return __builtin_amdgcn_exp2f(x);
}
#else
__device__ __forceinline__ float fast_exp2(float x) {
    float r;
    asm volatile("v_exp_f32 %0, %1\n\ts_nop 1" : "=v"(r) : "v"(x));
    return r;
}
#endif

// async global->LDS, 16B per lane (lds dst wave-uniform base, +lane*16)
__device__ __forceinline__ void gload16(const void* g, void* l) {
    __builtin_amdgcn_global_load_lds(
        (const __attribute__((address_space(1))) unsigned int*)g,
        (__attribute__((address_space(3))) unsigned int*)l, 16, 0, 0);
}

// ---------------------------------------------------------------------------
// Kernel 1: per-(b,c) mean / rsqrt(var+eps) over H*W = 4096
// ---------------------------------------------------------------------------
__global__ __launch_bounds__(1024)
void gn_stats_kernel(const float* __restrict__ x, float* __restrict__ stats) {
    __shared__ float red[32];
    const int bx  = blockIdx.x;
    const int tid = threadIdx.x;
    const float4* xp = (const float4*)(x + (size_t)bx * N_);
    float4 v = xp[tid];
    float s = (v.x + v.y) + (v.z + v.w);
    float q = (v.x * v.x + v.y * v.y) + (v.z * v.z + v.w * v.w);
#pragma unroll
    for (int off = 1; off < 64; off <<= 1) {
        s += __shfl_xor(s, off);
        q += __shfl_xor(q, off);
    }
    const int w = tid >> 6;
    if ((tid & 63) == 0) { red[w * 2] = s; red[w * 2 + 1] = q; }
    __syncthreads();
    if (w == 0) {
        const int lane = tid & 63;
        float sl = (lane < 16) ? red[lane * 2] : 0.f;
        float ql = (lane < 16) ? red[lane * 2 + 1] : 0.f;
#pragma unroll
        for (int off = 1; off < 16; off <<= 1) {
            sl += __shfl_xor(sl, off);
            ql += __shfl_xor(ql, off);
        }
        if (lane == 0) {
            float mu  = sl * (1.f / 4096.f);
            float var = ql * (1.f / 4096.f) - mu * mu;
            var = fmaxf(var, 0.f);
            stats[bx * 2]     = mu;
            stats[bx * 2 + 1] = 1.f / sqrtf(var + 1e-5f);
        }
    }
}

// ---------------------------------------------------------------------------
// Kernel 2: GroupNorm apply + QKV projections -> MFMA-frag layouts (r7).
// ---------------------------------------------------------------------------
__global__ __launch_bounds__(512)
void gn_qkv_kernel(const float* __restrict__ x, const float* __restrict__ stats,
                   const float* __restrict__ gnw, const float* __restrict__ gnb,
                   const float* __restrict__ wq, const float* __restrict__ bq,
                   const float* __restrict__ wk, const float* __restrict__ bk,
                   const float* __restrict__ wv, const float* __restrict__ bv,
                   unsigned short* __restrict__ Qt, unsigned short* __restrict__ Kf,
                   unsigned short* __restrict__ Vf) {
    __shared__ float xn[64 * 64];                 // [c][n] 16 KB
    __shared__ __align__(16) char vs[64 * 128];   // [m][d] bf16, XOR-swizzled, 8 KB
    const int t  = threadIdx.x;
    const int bx = blockIdx.x;
    const int b  = bx >> 6;
    const int n0 = (bx & 63) * 64;

    // ---- Phase A: load + normalize x tile ----
    {
        const int c  = t >> 3;
        const int nc = (t & 7) * 8;
        const float* xp = x + (size_t)(b * 64 + c) * N_ + n0 + nc;
        float4 xa = *(const float4*)(xp);
        float4 xb = *(const float4*)(xp + 4);
        float mu = stats[(b * 64 + c) * 2];
        float rs = stats[(b * 64 + c) * 2 + 1];
        float gw = gnw[c] * rs;
        float gb = gnb[c] - mu * gw;
        float* xr = xn + c * 64 + nc;
        xr[0] = xa.x * gw + gb; xr[1] = xa.y * gw + gb;
        xr[2] = xa.z * gw + gb; xr[3] = xa.w * gw + gb;
        xr[4] = xb.x * gw + gb; xr[5] = xb.y * gw + gb;
        xr[6] = xb.z * gw + gb; xr[7] = xb.w * gw + gb;
    }
    __syncthreads();

    // ---- Phase B: per (n, 8d) dot products ----
    const int n    = t & 63;
    const int dblk = __builtin_amdgcn_readfirstlane(t >> 6);
    const int d0   = dblk * 8;

    float aq[8], ak[8], av[8];
#pragma unroll
    for (int i = 0; i < 8; ++i) { aq[i] = 0.f; ak[i] = 0.f; av[i] = 0.f; }

#pragma unroll 4
    for (int c = 0; c < 64; ++c) {
        const float xv = xn[c * 64 + n];
#pragma unroll
        for (int i = 0; i < 8; ++i) {
            aq[i] += wq[(d0 + i) * 64 + c] * xv;
            ak[i] += wk[(d0 + i) * 64 + c] * xv;
            av[i] += wv[(d0 + i) * 64 + c] * xv;
        }
    }

    const float QS = 0.18033688011112042f;  // 0.125 * log2(e): exp2-domain logits
    const int m = n0 + n;
    u16x8 qv, kv, vb;
#pragma unroll
    for (int i = 0; i < 8; ++i) {
        qv[i] = f2bf((aq[i] + bq[d0 + i]) * QS);
        kv[i] = f2bf(ak[i] + bk[d0 + i]);
        vb[i] = f2bf(av[i] + bv[d0 + i]);
    }
    // Q: [n][d] row store (16B)
    *(u16x8*)(Qt + ((size_t)(b * N_ + m)) * 64 + d0) = qv;
    // K: direct frag store
    {
        const int kc = dblk >> 1, h = dblk & 1, mt = m >> 5;
        *(u16x8*)(Kf + ((size_t)((b * 128 + mt) * 4 + kc)) * 512
                     + (h * 32 + (m & 31)) * 8) = kv;
    }
    // V: swizzled LDS stage
    *(u16x8*)(vs + n * 128 + ((dblk * 16) ^ ((n & 7) << 4))) = vb;
    __syncthreads();

    // ---- Phase C: frag-ordered Vf copyout (one 16B store per thread) ----
    {
        const int mc_l = t >> 7;            // 0..3
        const int dt   = (t >> 6) & 1;
        const int lp   = t & 63;
        const int hp   = lp >> 5;
        const int dcol = (lp & 31) + dt * 32;
        const int cbase = (dcol & ~7) * 2;
        const int clow  = (dcol & 7) * 2;
        u16x8 tmp;
#pragma unroll
        for (int j = 0; j < 8; ++j) {
            const int ml = mc_l * 16 + hp * 8 + j;   // ml&7 == j
            tmp[j] = *(const unsigned short*)(
                vs + ml * 128 + (cbase ^ (j << 4)) + clow);
        }
        *(u16x8*)(Vf + ((size_t)((b * 256 + (n0 >> 4) + mc_l) * 2 + dt)) * 512
                     + lp * 8) = tmp;
    }
}

// ---------------------------------------------------------------------------
// Kernel 3: attention + fused output projection, BARRIER-FREE main loop.
// grid = 256 blocks (b = bid&3, qc = bid>>2: 64 q-rows), 256 thr (4 waves).
// Wave wvu: ALL 64 q-rows (2 subtiles, r16 dual-chain body) x m-quarter
// [wvu*1024, +1024), with a PRIVATE 32KB double-buffered K/V LDS stream:
// no __syncthreads in the loop — per-wave s_waitcnt vmcnt(0) only.
// Epilogue: f32 LDS merge of 4 quarters -> normalize -> atile[64][65] ->
// in-block out = wo @ att + bo (coalesced stores). 3 block barriers total.
// LDS 128KB -> 1 block/CU (grid 256 = exactly 1/CU).
// ---------------------------------------------------------------------------
__global__ __launch_bounds__(256, 1)
void attn_kernel(const unsigned short* __restrict__ Qt,
                 const unsigned short* __restrict__ Kf,
                 const unsigned short* __restrict__ Vf,
                 const float* __restrict__ wo, const float* __restrict__ bo,
                 float* __restrict__ out) {
    __shared__ __align__(16) char smem[131072];
    const int tid  = threadIdx.x;
    const int lane = tid & 63;
    const int wvu  = __builtin_amdgcn_readfirstlane(tid >> 6);   // m-quarter id
    const int c    = lane & 31;
    const int h    = lane >> 5;
    const int bid  = blockIdx.x;
    const int b    = bid & 3;
    const int qc   = bid >> 2;
    const int n0   = qc * 64;

    // Q B-frags for both 32-row subtiles (same q-rows for all 4 waves)
    const unsigned short* qp = Qt + (size_t)(b * N_ + n0 + c) * 64 + h * 8;
    bf16x8 qa0[4], qa1[4];
#pragma unroll
    for (int kc = 0; kc < 4; ++kc) {
        qa0[kc] = *(const bf16x8*)(qp + kc * 16);
        qa1[kc] = *(const bf16x8*)(qp + 32 * 64 + kc * 16);
    }

    f32x16 o00, o01, o10, o11;
#pragma unroll
    for (int i = 0; i < 16; ++i) { o00[i] = 0.f; o01[i] = 0.f; o10[i] = 0.f; o11[i] = 0.f; }
    float lsA0 = 0.f, lsA1 = 0.f, lsB0 = 0.f, lsB1 = 0.f;

    const int lof = lane * 16;
    char* sbase = smem + wvu * 32768;   // private stream: 2 x 16KB (K 8K | V 8K)
    // K/V quarter base: each quarter = 1024 m = 128KB in both frag layouts
    const char* kTn = (const char*)Kf + (size_t)b * 524288 + (size_t)wvu * 131072;
    const char* vTn = (const char*)Vf + (size_t)b * 524288 + (size_t)wvu * 131072;

    // ---- prologue: stage tile 0 into buf0 (16 x 1KB chunks) ----
#pragma unroll
    for (int j = 0; j < 8; ++j) {
        gload16(kTn + j * 1024 + lof, sbase + j * 1024);
        gload16(vTn + j * 1024 + lof, sbase + 8192 + j * 1024);
    }
    asm volatile("s_waitcnt vmcnt(0)" ::: "memory");
    __builtin_amdgcn_sched_barrier(0);

    for (int t = 0; t < 16; ++t) {
        char* buf = sbase + ((t & 1) << 14);
        // ---- issue next-tile async stage into the other buffer ----
        if (t + 1 < 16) {
            kTn += 8192;
            vTn += 8192;
            char* dst = sbase + (((t & 1) ^ 1) << 14);
#pragma unroll
            for (int j = 0; j < 8; ++j) {
                gload16(kTn + j * 1024 + lof, dst + j * 1024);
                gload16(vTn + j * 1024 + lof, dst + 8192 + j * 1024);
            }
        }

        // ---- compute current tile: 2 m-groups, dual-subtile (r16 body) ----
#pragma unroll
        for (int g = 0; g < 2; ++g) {
            const char* kb = buf + g * 4096 + lof;
            bf16x8 kf0 = *(const bf16x8*)(kb);
            bf16x8 kf1 = *(const bf16x8*)(kb + 1024);
            bf16x8 kf2 = *(const bf16x8*)(kb + 2048);
            bf16x8 kf3 = *(const bf16x8*)(kb + 3072);
            f32x16 sa0, sa1;
#pragma unroll
            for (int i = 0; i < 16; ++i) { sa0[i] = 0.f; sa1[i] = 0.f; }
            sa0 = __builtin_amdgcn_mfma_f32_32x32x16_bf16(kf0, qa0[0], sa0, 0, 0, 0);
            sa1 = __builtin_amdgcn_mfma_f32_32x32x16_bf16(kf0, qa1[0], sa1, 0, 0, 0);
            sa0 = __builtin_amdgcn_mfma_f32_32x32x16_bf16(kf1, qa0[1], sa0, 0, 0, 0);
            sa1 = __builtin_amdgcn_mfma_f32_32x32x16_bf16(kf1, qa1[1], sa1, 0, 0, 0);
            sa0 = __builtin_amdgcn_mfma_f32_32x32x16_bf16(kf2, qa0[2], sa0, 0, 0, 0);
            sa1 = __builtin_amdgcn_mfma_f32_32x32x16_bf16(kf2, qa1[2], sa1, 0, 0, 0);
            sa0 = __builtin_amdgcn_mfma_f32_32x32x16_bf16(kf3, qa0[3], sa0, 0, 0, 0);
            sa1 = __builtin_amdgcn_mfma_f32_32x32x16_bf16(kf3, qa1[3], sa1, 0, 0, 0);

            // P = exp2(S^T) both subtiles; 4 independent sum chains
#pragma unroll
            for (int i = 0; i < 16; i += 2) {
                float pA0 = fast_exp2(sa0[i]);
                float pA1 = fast_exp2(sa0[i + 1]);
                float pB0 = fast_exp2(sa1[i]);
                float pB1 = fast_exp2(sa1[i + 1]);
                sa0[i] = pA0; sa0[i + 1] = pA1;
                sa1[i] = pB0; sa1[i + 1] = pB1;
                lsA0 += pA0; lsA1 += pA1;
                lsB0 += pB0; lsB1 += pB1;
            }
            // pack both subtiles to bf16 pairs and swap halves
            unsigned dwa[8], dwb[8];
#pragma unroll
            for (int i = 0; i < 8; ++i) {
                asm("v_cvt_pk_bf16_f32 %0, %1, %2"
                    : "=v"(dwa[i]) : "v"(sa0[2 * i]), "v"(sa0[2 * i + 1]));
                asm("v_cvt_pk_bf16_f32 %0, %1, %2"
                    : "=v"(dwb[i]) : "v"(sa1[2 * i]), "v"(sa1[2 * i + 1]));
            }
            asm("v_permlane32_swap_b32 %0, %1" : "+v"(dwa[0]), "+v"(dwa[2]));
            asm("v_permlane32_swap_b32 %0, %1" : "+v"(dwa[1]), "+v"(dwa[3]));
            asm("v_permlane32_swap_b32 %0, %1" : "+v"(dwa[4]), "+v"(dwa[6]));
            asm("v_permlane32_swap_b32 %0, %1" : "+v"(dwa[5]), "+v"(dwa[7]));
            asm("v_permlane32_swap_b32 %0, %1" : "+v"(dwb[0]), "+v"(dwb[2]));
            asm("v_permlane32_swap_b32 %0, %1" : "+v"(dwb[1]), "+v"(dwb[3]));
            asm("v_permlane32_swap_b32 %0, %1" : "+v"(dwb[4]), "+v"(dwb[6]));
            asm("v_permlane32_swap_b32 %0, %1" : "+v"(dwb[5]), "+v"(dwb[7]));
            bf16x8 pa0 = __builtin_bit_cast(bf16x8, (u32x4){dwa[0], dwa[1], dwa[2], dwa[3]});
            bf16x8 pa1 = __builtin_bit_cast(bf16x8, (u32x4){dwa[4], dwa[5], dwa[6], dwa[7]});
            bf16x8 pb0 = __builtin_bit_cast(bf16x8, (u32x4){dwb[0], dwb[1], dwb[2], dwb[3]});
            bf16x8 pb1 = __builtin_bit_cast(bf16x8, (u32x4){dwb[4], dwb[5], dwb[6], dwb[7]});

            // PV both subtiles from the SAME V frag reads (4 acc chains)
            const char* vbp = buf + 8192 + g * 4096 + lof;
            bf16x8 vf0 = *(const bf16x8*)(vbp);
            bf16x8 vf1 = *(const bf16x8*)(vbp + 1024);
            bf16x8 vf2 = *(const bf16x8*)(vbp + 2048);
            bf16x8 vf3 = *(const bf16x8*)(vbp + 3072);
            o00 = __builtin_amdgcn_mfma_f32_32x32x16_bf16(vf0, pa0, o00, 0, 0, 0);
            o10 = __builtin_amdgcn_mfma_f32_32x32x16_bf16(vf0, pb0, o10, 0, 0, 0);
            o01 = __builtin_amdgcn_mfma_f32_32x32x16_bf16(vf1, pa0, o01, 0, 0, 0);
            o11 = __builtin_amdgcn_mfma_f32_32x32x16_bf16(vf1, pb0, o11, 0, 0, 0);
            o00 = __builtin_amdgcn_mfma_f32_32x32x16_bf16(vf2, pa1, o00, 0, 0, 0);
            o10 = __builtin_amdgcn_mfma_f32_32x32x16_bf16(vf2, pb1, o10, 0, 0, 0);
            o01 = __builtin_amdgcn_mfma_f32_32x32x16_bf16(vf3, pa1, o01, 0, 0, 0);
            o11 = __builtin_amdgcn_mfma_f32_32x32x16_bf16(vf3, pb1, o11, 0, 0, 0);
        }

        // per-wave drain of the next tile's staging (NO block barrier)
        asm volatile("s_waitcnt vmcnt(0)" ::: "memory");
        __builtin_amdgcn_sched_barrier(0);
    }

    // per-wave rowsums (col q = own half + other half), per subtile
    float lsA = lsA0 + lsA1;
    float lsB = lsB0 + lsB1;
    float rsA = lsA + __shfl_xor(lsA, 32);
    float rsB = lsB + __shfl_xor(lsB, 32);

    // ---- epilogue: merge 4 m-quarters in LDS (f32), normalize, project ----
    __syncthreads();                          // all streams dead; LDS reusable
    float* mrg   = (float*)smem + wvu * 4096; // [64 d][64 q] f32 per wave (16KB)
    float* lsm   = (float*)(smem + 65536);    // [4 wave][64 q]
    float* atile = (float*)(smem + 66560);    // [64 d][65] f32
#pragma unroll
    for (int r = 0; r < 16; ++r) {
        const int row = (r & 3) + 8 * (r >> 2) + 4 * h;
        mrg[row * 64 + c]             = o00[r];
        mrg[(row + 32) * 64 + c]      = o01[r];
        mrg[row * 64 + 32 + c]        = o10[r];
        mrg[(row + 32) * 64 + 32 + c] = o11[r];
    }
    if (h == 0) {
        lsm[wvu * 64 + c]      = rsA;
        lsm[wvu * 64 + 32 + c] = rsB;
    }
    __syncthreads();
    {   // wave wvu merges quadrant (dh = wvu>>1 of d, qh = wvu&1 of q)
        const int dh = wvu >> 1, qh = wvu & 1;
        const int qq = qh * 32 + c;
        const float lt = lsm[qq] + lsm[64 + qq] + lsm[128 + qq] + lsm[192 + qq];
        const float inv = 1.f / lt;
        const float* m0 = (const float*)smem;
#pragma unroll
        for (int r = 0; r < 16; ++r) {
            const int row = dh * 32 + (r & 3) + 8 * (r >> 2) + 4 * h;
            const int idx = row * 64 + qq;
            float sum = (m0[idx] + m0[4096 + idx])
                      + (m0[8192 + idx] + m0[12288 + idx]);
            atile[row * 65 + qq] = sum * inv;
        }
    }
    __syncthreads();
    {   // projection: out[e][n0+n] = bo[e] + sum_d wo[e][d] * atile[d][n]
        const int n  = tid & 63;
        const int e0 = wvu * 16;
        float acc[16];
#pragma unroll
        for (int i = 0; i < 16; ++i) acc[i] = bo[e0 + i];
#pragma unroll 8
        for (int d = 0; d < 64; ++d) {
            const float xv = atile[d * 65 + n];
#pragma unroll
            for (int i = 0; i < 16; ++i) acc[i] += wo[(e0 + i) * 64 + d] * xv;
        }
#pragma unroll
        for (int i = 0; i < 16; ++i)
            out[((size_t)(b * 64 + e0 + i) << 12) + n0 + n] = acc[i];
    }
}

// ---------------------------------------------------------------------------
extern "C" void kernel_launch(void* const* d_in, const int* in_sizes, int n_in,
                              void* d_out, int out_size, void* d_ws, size_t ws_size,
                              hipStream_t stream) {
    const float* x   = (const float*)d_in[0];
    const float* gnw = (const float*)d_in[1];
    const float* gnb = (const float*)d_in[2];
    const float* wq  = (const float*)d_in[3];
    const float* bq  = (const float*)d_in[4];
    const float* wk  = (const float*)d_in[5];
    const float* bk  = (const float*)d_in[6];
    const float* wv  = (const float*)d_in[7];
    const float* bv  = (const float*)d_in[8];
    const float* wo  = (const float*)d_in[9];
    const float* bo  = (const float*)d_in[10];
    float* out = (float*)d_out;

    char* wsb = (char*)d_ws;
    float*          stats = (float*)wsb;                                  //   2 KB
    unsigned short* Qt    = (unsigned short*)(wsb + 2048);                //   2 MB
    unsigned short* Kf    = (unsigned short*)(wsb + 2048 + 2097152);      //   2 MB
    unsigned short* Vf    = (unsigned short*)(wsb + 2048 + 2 * 2097152);  //   2 MB

    gn_stats_kernel<<<dim3(B_ * C_), dim3(1024), 0, stream>>>(x, stats);
    gn_qkv_kernel<<<dim3(B_ * 64), dim3(512), 0, stream>>>(
        x, stats, gnw, gnb, wq, bq, wk, bk, wv, bv, Qt, Kf, Vf);
    attn_kernel<<<dim3(B_ * 64), dim3(256), 0, stream>>>(
        Qt, Kf, Vf, wo, bo, out);
}

// Round 21
// 56.105 us; speedup vs baseline: 1.0892x; 1.0892x over previous
//
#include <hip/hip_runtime.h>

// ---------------------------------------------------------------------------
// AttentionHead: GroupNorm -> QKV 1x1 conv -> softmax attention -> 1x1 conv.
// Round 21: r20's fused barrier-free design at 2 waves/SIMD. 512-thr blocks
// (8 waves); each wave owns an m-EIGHTH (512 m) with a private 16KB dbuf
// stream (tile 32m: K 4KB + V 4KB). LDS 128KB, 1 block/CU, but 8 waves =
// 2/SIMD (r20's 1/SIMD exposed all latencies -> 45.5us attn). Main loop
// unchanged otherwise: gload_lds staging, per-wave vmcnt(0), dual-subtile
// MFMA body, in-register softmax, fused f32 merge + projection epilogue.
// gn_stats / gn_qkv byte-identical to r19-verified.
// ---------------------------------------------------------------------------

#define B_ 4
#define C_ 64
#define D_ 64
#define N_ 4096

using bf16x8 = __attribute__((ext_vector_type(8))) short;     // 8 bf16 = 4 VGPR
using u16x8  = __attribute__((ext_vector_type(8))) unsigned short;
using u32x4  = __attribute__((ext_vector_type(4))) unsigned int;
using f32x16 = __attribute__((ext_vector_type(16))) float;

// round-to-nearest-even f32 -> bf16 bits
__device__ __forceinline__ unsigned short f2bf(float f) {
    unsigned u = __builtin_bit_cast(unsigned, f);
    u = (u + 0x7FFFu + ((u >> 16) & 1u)) >> 16;
    return (unsigned short)u;
}

// single-instruction exp2: builtin (backend-hazard-managed) or asm + s_nop
#if __has_builtin(__builtin_amdgcn_exp2f)
__device__ __forceinline__ float fast_exp2(float x) {
    return __builtin_amdgcn_exp2f(x);
}
#else
__device__ __forceinline__ float fast_exp2(float x) {
    float r;
    asm volatile("v_exp_f32 %0, %1\n\ts_nop 1" : "=v"(r) : "v"(x));
    return r;
}
#endif

// async global->LDS, 16B per lane (lds dst wave-uniform base, +lane*16)
__device__ __forceinline__ void gload16(const void* g, void* l) {
    __builtin_amdgcn_global_load_lds(
        (const __attribute__((address_space(1))) unsigned int*)g,
        (__attribute__((address_space(3))) unsigned int*)l, 16, 0, 0);
}

// ---------------------------------------------------------------------------
// Kernel 1: per-(b,c) mean / rsqrt(var+eps) over H*W = 4096
// ---------------------------------------------------------------------------
__global__ __launch_bounds__(1024)
void gn_stats_kernel(const float* __restrict__ x, float* __restrict__ stats) {
    __shared__ float red[32];
    const int bx  = blockIdx.x;
    const int tid = threadIdx.x;
    const float4* xp = (const float4*)(x + (size_t)bx * N_);
    float4 v = xp[tid];
    float s = (v.x + v.y) + (v.z + v.w);
    float q = (v.x * v.x + v.y * v.y) + (v.z * v.z + v.w * v.w);
#pragma unroll
    for (int off = 1; off < 64; off <<= 1) {
        s += __shfl_xor(s, off);
        q += __shfl_xor(q, off);
    }
    const int w = tid >> 6;
    if ((tid & 63) == 0) { red[w * 2] = s; red[w * 2 + 1] = q; }
    __syncthreads();
    if (w == 0) {
        const int lane = tid & 63;
        float sl = (lane < 16) ? red[lane * 2] : 0.f;
        float ql = (lane < 16) ? red[lane * 2 + 1] : 0.f;
#pragma unroll
        for (int off = 1; off < 16; off <<= 1) {
            sl += __shfl_xor(sl, off);
            ql += __shfl_xor(ql, off);
        }
        if (lane == 0) {
            float mu  = sl * (1.f / 4096.f);
            float var = ql * (1.f / 4096.f) - mu * mu;
            var = fmaxf(var, 0.f);
            stats[bx * 2]     = mu;
            stats[bx * 2 + 1] = 1.f / sqrtf(var + 1e-5f);
        }
    }
}

// ---------------------------------------------------------------------------
// Kernel 2: GroupNorm apply + QKV projections -> MFMA-frag layouts (r7).
// ---------------------------------------------------------------------------
__global__ __launch_bounds__(512)
void gn_qkv_kernel(const float* __restrict__ x, const float* __restrict__ stats,
                   const float* __restrict__ gnw, const float* __restrict__ gnb,
                   const float* __restrict__ wq, const float* __restrict__ bq,
                   const float* __restrict__ wk, const float* __restrict__ bk,
                   const float* __restrict__ wv, const float* __restrict__ bv,
                   unsigned short* __restrict__ Qt, unsigned short* __restrict__ Kf,
                   unsigned short* __restrict__ Vf) {
    __shared__ float xn[64 * 64];                 // [c][n] 16 KB
    __shared__ __align__(16) char vs[64 * 128];   // [m][d] bf16, XOR-swizzled, 8 KB
    const int t  = threadIdx.x;
    const int bx = blockIdx.x;
    const int b  = bx >> 6;
    const int n0 = (bx & 63) * 64;

    // ---- Phase A: load + normalize x tile ----
    {
        const int c  = t >> 3;
        const int nc = (t & 7) * 8;
        const float* xp = x + (size_t)(b * 64 + c) * N_ + n0 + nc;
        float4 xa = *(const float4*)(xp);
        float4 xb = *(const float4*)(xp + 4);
        float mu = stats[(b * 64 + c) * 2];
        float rs = stats[(b * 64 + c) * 2 + 1];
        float gw = gnw[c] * rs;
        float gb = gnb[c] - mu * gw;
        float* xr = xn + c * 64 + nc;
        xr[0] = xa.x * gw + gb; xr[1] = xa.y * gw + gb;
        xr[2] = xa.z * gw + gb; xr[3] = xa.w * gw + gb;
        xr[4] = xb.x * gw + gb; xr[5] = xb.y * gw + gb;
        xr[6] = xb.z * gw + gb; xr[7] = xb.w * gw + gb;
    }
    __syncthreads();

    // ---- Phase B: per (n, 8d) dot products ----
    const int n    = t & 63;
    const int dblk = __builtin_amdgcn_readfirstlane(t >> 6);
    const int d0   = dblk * 8;

    float aq[8], ak[8], av[8];
#pragma unroll
    for (int i = 0; i < 8; ++i) { aq[i] = 0.f; ak[i] = 0.f; av[i] = 0.f; }

#pragma unroll 4
    for (int c = 0; c < 64; ++c) {
        const float xv = xn[c * 64 + n];
#pragma unroll
        for (int i = 0; i < 8; ++i) {
            aq[i] += wq[(d0 + i) * 64 + c] * xv;
            ak[i] += wk[(d0 + i) * 64 + c] * xv;
            av[i] += wv[(d0 + i) * 64 + c] * xv;
        }
    }

    const float QS = 0.18033688011112042f;  // 0.125 * log2(e): exp2-domain logits
    const int m = n0 + n;
    u16x8 qv, kv, vb;
#pragma unroll
    for (int i = 0; i < 8; ++i) {
        qv[i] = f2bf((aq[i] + bq[d0 + i]) * QS);
        kv[i] = f2bf(ak[i] + bk[d0 + i]);
        vb[i] = f2bf(av[i] + bv[d0 + i]);
    }
    // Q: [n][d] row store (16B)
    *(u16x8*)(Qt + ((size_t)(b * N_ + m)) * 64 + d0) = qv;
    // K: direct frag store
    {
        const int kc = dblk >> 1, h = dblk & 1, mt = m >> 5;
        *(u16x8*)(Kf + ((size_t)((b * 128 + mt) * 4 + kc)) * 512
                     + (h * 32 + (m & 31)) * 8) = kv;
    }
    // V: swizzled LDS stage
    *(u16x8*)(vs + n * 128 + ((dblk * 16) ^ ((n & 7) << 4))) = vb;
    __syncthreads();

    // ---- Phase C: frag-ordered Vf copyout (one 16B store per thread) ----
    {
        const int mc_l = t >> 7;            // 0..3
        const int dt   = (t >> 6) & 1;
        const int lp   = t & 63;
        const int hp   = lp >> 5;
        const int dcol = (lp & 31) + dt * 32;
        const int cbase = (dcol & ~7) * 2;
        const int clow  = (dcol & 7) * 2;
        u16x8 tmp;
#pragma unroll
        for (int j = 0; j < 8; ++j) {
            const int ml = mc_l * 16 + hp * 8 + j;   // ml&7 == j
            tmp[j] = *(const unsigned short*)(
                vs + ml * 128 + (cbase ^ (j << 4)) + clow);
        }
        *(u16x8*)(Vf + ((size_t)((b * 256 + (n0 >> 4) + mc_l) * 2 + dt)) * 512
                     + lp * 8) = tmp;
    }
}

// ---------------------------------------------------------------------------
// Kernel 3: attention + fused projection; 8 waves, barrier-free main loop.
// grid = 256 blocks (b = bid&3, qc = bid>>2: 64 q-rows), 512 thr (8 waves).
// Wave wvu: ALL 64 q-rows (dual subtile) x m-eighth [wvu*512, +512) via a
// PRIVATE 16KB dbuf stream (tile 32m: K 4KB | V 4KB). No block barriers in
// the loop; per-wave s_waitcnt vmcnt(0). Epilogue: two-stage f32 LDS merge
// (waves 0-3 write, 4-7 add), normalize -> atile, 512-thr projection.
// LDS 128KB -> 1 block/CU, 8 waves = 2/SIMD.
// ---------------------------------------------------------------------------
__global__ __launch_bounds__(512, 2)
void attn_kernel(const unsigned short* __restrict__ Qt,
                 const unsigned short* __restrict__ Kf,
                 const unsigned short* __restrict__ Vf,
                 const float* __restrict__ wo, const float* __restrict__ bo,
                 float* __restrict__ out) {
    __shared__ __align__(16) char smem[131072];
    const int tid  = threadIdx.x;
    const int lane = tid & 63;
    const int wvu  = __builtin_amdgcn_readfirstlane(tid >> 6);   // m-eighth 0..7
    const int c    = lane & 31;
    const int h    = lane >> 5;
    const int bid  = blockIdx.x;
    const int b    = bid & 3;
    const int qc   = bid >> 2;
    const int n0   = qc * 64;

    // Q B-frags for both 32-row subtiles (same q-rows for all 8 waves)
    const unsigned short* qp = Qt + (size_t)(b * N_ + n0 + c) * 64 + h * 8;
    bf16x8 qa0[4], qa1[4];
#pragma unroll
    for (int kc = 0; kc < 4; ++kc) {
        qa0[kc] = *(const bf16x8*)(qp + kc * 16);
        qa1[kc] = *(const bf16x8*)(qp + 32 * 64 + kc * 16);
    }

    f32x16 o00, o01, o10, o11;
#pragma unroll
    for (int i = 0; i < 16; ++i) { o00[i] = 0.f; o01[i] = 0.f; o10[i] = 0.f; o11[i] = 0.f; }
    float lsA0 = 0.f, lsA1 = 0.f, lsB0 = 0.f, lsB1 = 0.f;

    const int lof = lane * 16;
    char* sbase = smem + wvu * 16384;   // private stream: 2 x 8KB (K 4K | V 4K)
    // m-eighth = 512 m = 16 mt (64KB in Kf) = 32 mc (64KB in Vf)
    const char* kTn = (const char*)Kf + (size_t)b * 524288 + (size_t)wvu * 65536;
    const char* vTn = (const char*)Vf + (size_t)b * 524288 + (size_t)wvu * 65536;

    // ---- prologue: stage tile 0 into buf0 (8 x 1KB chunks) ----
#pragma unroll
    for (int j = 0; j < 4; ++j) {
        gload16(kTn + j * 1024 + lof, sbase + j * 1024);
        gload16(vTn + j * 1024 + lof, sbase + 4096 + j * 1024);
    }
    asm volatile("s_waitcnt vmcnt(0)" ::: "memory");
    __builtin_amdgcn_sched_barrier(0);

    for (int t = 0; t < 16; ++t) {
        char* buf = sbase + ((t & 1) << 13);
        // ---- issue next-tile async stage into the other buffer ----
        if (t + 1 < 16) {
            kTn += 4096;
            vTn += 4096;
            char* dst = sbase + (((t & 1) ^ 1) << 13);
#pragma unroll
            for (int j = 0; j < 4; ++j) {
                gload16(kTn + j * 1024 + lof, dst + j * 1024);
                gload16(vTn + j * 1024 + lof, dst + 4096 + j * 1024);
            }
        }

        // ---- compute current 32-m tile, dual-subtile (r16 body, g=0) ----
        const char* kb = buf + lof;
        bf16x8 kf0 = *(const bf16x8*)(kb);
        bf16x8 kf1 = *(const bf16x8*)(kb + 1024);
        bf16x8 kf2 = *(const bf16x8*)(kb + 2048);
        bf16x8 kf3 = *(const bf16x8*)(kb + 3072);
        f32x16 sa0, sa1;
#pragma unroll
        for (int i = 0; i < 16; ++i) { sa0[i] = 0.f; sa1[i] = 0.f; }
        sa0 = __builtin_amdgcn_mfma_f32_32x32x16_bf16(kf0, qa0[0], sa0, 0, 0, 0);
        sa1 = __builtin_amdgcn_mfma_f32_32x32x16_bf16(kf0, qa1[0], sa1, 0, 0, 0);
        sa0 = __builtin_amdgcn_mfma_f32_32x32x16_bf16(kf1, qa0[1], sa0, 0, 0, 0);
        sa1 = __builtin_amdgcn_mfma_f32_32x32x16_bf16(kf1, qa1[1], sa1, 0, 0, 0);
        sa0 = __builtin_amdgcn_mfma_f32_32x32x16_bf16(kf2, qa0[2], sa0, 0, 0, 0);
        sa1 = __builtin_amdgcn_mfma_f32_32x32x16_bf16(kf2, qa1[2], sa1, 0, 0, 0);
        sa0 = __builtin_amdgcn_mfma_f32_32x32x16_bf16(kf3, qa0[3], sa0, 0, 0, 0);
        sa1 = __builtin_amdgcn_mfma_f32_32x32x16_bf16(kf3, qa1[3], sa1, 0, 0, 0);

        // P = exp2(S^T) both subtiles; 4 independent sum chains
#pragma unroll
        for (int i = 0; i < 16; i += 2) {
            float pA0 = fast_exp2(sa0[i]);
            float pA1 = fast_exp2(sa0[i + 1]);
            float pB0 = fast_exp2(sa1[i]);
            float pB1 = fast_exp2(sa1[i + 1]);
            sa0[i] = pA0; sa0[i + 1] = pA1;
            sa1[i] = pB0; sa1[i + 1] = pB1;
            lsA0 += pA0; lsA1 += pA1;
            lsB0 += pB0; lsB1 += pB1;
        }
        // pack both subtiles to bf16 pairs and swap halves
        unsigned dwa[8], dwb[8];
#pragma unroll
        for (int i = 0; i < 8; ++i) {
            asm("v_cvt_pk_bf16_f32 %0, %1, %2"
                : "=v"(dwa[i]) : "v"(sa0[2 * i]), "v"(sa0[2 * i + 1]));
            asm("v_cvt_pk_bf16_f32 %0, %1, %2"
                : "=v"(dwb[i]) : "v"(sa1[2 * i]), "v"(sa1[2 * i + 1]));
        }
        asm("v_permlane32_swap_b32 %0, %1" : "+v"(dwa[0]), "+v"(dwa[2]));
        asm("v_permlane32_swap_b32 %0, %1" : "+v"(dwa[1]), "+v"(dwa[3]));
        asm("v_permlane32_swap_b32 %0, %1" : "+v"(dwa[4]), "+v"(dwa[6]));
        asm("v_permlane32_swap_b32 %0, %1" : "+v"(dwa[5]), "+v"(dwa[7]));
        asm("v_permlane32_swap_b32 %0, %1" : "+v"(dwb[0]), "+v"(dwb[2]));
        asm("v_permlane32_swap_b32 %0, %1" : "+v"(dwb[1]), "+v"(dwb[3]));
        asm("v_permlane32_swap_b32 %0, %1" : "+v"(dwb[4]), "+v"(dwb[6]));
        asm("v_permlane32_swap_b32 %0, %1" : "+v"(dwb[5]), "+v"(dwb[7]));
        bf16x8 pa0 = __builtin_bit_cast(bf16x8, (u32x4){dwa[0], dwa[1], dwa[2], dwa[3]});
        bf16x8 pa1 = __builtin_bit_cast(bf16x8, (u32x4){dwa[4], dwa[5], dwa[6], dwa[7]});
        bf16x8 pb0 = __builtin_bit_cast(bf16x8, (u32x4){dwb[0], dwb[1], dwb[2], dwb[3]});
        bf16x8 pb1 = __builtin_bit_cast(bf16x8, (u32x4){dwb[4], dwb[5], dwb[6], dwb[7]});

        // PV both subtiles from the SAME V frag reads (4 acc chains)
        const char* vbp = buf + 4096 + lof;
        bf16x8 vf0 = *(const bf16x8*)(vbp);
        bf16x8 vf1 = *(const bf16x8*)(vbp + 1024);
        bf16x8 vf2 = *(const bf16x8*)(vbp + 2048);
        bf16x8 vf3 = *(const bf16x8*)(vbp + 3072);
        o00 = __builtin_amdgcn_mfma_f32_32x32x16_bf16(vf0, pa0, o00, 0, 0, 0);
        o10 = __builtin_amdgcn_mfma_f32_32x32x16_bf16(vf0, pb0, o10, 0, 0, 0);
        o01 = __builtin_amdgcn_mfma_f32_32x32x16_bf16(vf1, pa0, o01, 0, 0, 0);
        o11 = __builtin_amdgcn_mfma_f32_32x32x16_bf16(vf1, pb0, o11, 0, 0, 0);
        o00 = __builtin_amdgcn_mfma_f32_32x32x16_bf16(vf2, pa1, o00, 0, 0, 0);
        o10 = __builtin_amdgcn_mfma_f32_32x32x16_bf16(vf2, pb1, o10, 0, 0, 0);
        o01 = __builtin_amdgcn_mfma_f32_32x32x16_bf16(vf3, pa1, o01, 0, 0, 0);
        o11 = __builtin_amdgcn_mfma_f32_32x32x16_bf16(vf3, pb1, o11, 0, 0, 0);

        // per-wave drain of the next tile's staging (NO block barrier)
        asm volatile("s_waitcnt vmcnt(0)" ::: "memory");
        __builtin_amdgcn_sched_barrier(0);
    }

    // per-wave rowsums (col q = own half + other half), per subtile
    float lsA = lsA0 + lsA1;
    float lsB = lsB0 + lsB1;
    float rsA = lsA + __shfl_xor(lsA, 32);
    float rsB = lsB + __shfl_xor(lsB, 32);

    // ---- epilogue: two-stage f32 merge, normalize, in-block projection ----
    __syncthreads();                          // all streams dead; LDS reusable
    float* lsm   = (float*)(smem + 65536);    // [8 wave][64 q] (dead stream)
    float* atile = (float*)(smem + 68608);    // [64 d][65] f32
    if (wvu < 4) {                            // stage A: waves 0-3 write
        float* mrg = (float*)(smem + wvu * 16384);
#pragma unroll
        for (int r = 0; r < 16; ++r) {
            const int row = (r & 3) + 8 * (r >> 2) + 4 * h;
            mrg[row * 64 + c]             = o00[r];
            mrg[(row + 32) * 64 + c]      = o01[r];
            mrg[row * 64 + 32 + c]        = o10[r];
            mrg[(row + 32) * 64 + 32 + c] = o11[r];
        }
    }
    if (h == 0) {
        lsm[wvu * 64 + c]      = rsA;
        lsm[wvu * 64 + 32 + c] = rsB;
    }
    __syncthreads();
    if (wvu >= 4) {                           // stage B: waves 4-7 add
        float* mrg = (float*)(smem + (wvu - 4) * 16384);
#pragma unroll
        for (int r = 0; r < 16; ++r) {
            const int row = (r & 3) + 8 * (r >> 2) + 4 * h;
            mrg[row * 64 + c]             += o00[r];
            mrg[(row + 32) * 64 + c]      += o01[r];
            mrg[row * 64 + 32 + c]        += o10[r];
            mrg[(row + 32) * 64 + 32 + c] += o11[r];
        }
    }
    __syncthreads();
    if (wvu < 4) {   // quadrant merge of the 4 buffers + normalize -> atile
        const int dh = wvu >> 1, qh = wvu & 1;
        const int qq = qh * 32 + c;
        float lt = 0.f;
#pragma unroll
        for (int k = 0; k < 8; ++k) lt += lsm[k * 64 + qq];
        const float inv = 1.f / lt;
        const float* m0 = (const float*)smem;
#pragma unroll
        for (int r = 0; r < 16; ++r) {
            const int row = dh * 32 + (r & 3) + 8 * (r >> 2) + 4 * h;
            const int idx = row * 64 + qq;
            float sum = (m0[idx] + m0[4096 + idx])
                      + (m0[8192 + idx] + m0[12288 + idx]);
            atile[row * 65 + qq] = sum * inv;
        }
    }
    __syncthreads();
    {   // projection: 512 thr; thread (n = tid&63, 8 e's)
        const int n  = tid & 63;
        const int e0 = (tid >> 6) * 8;
        float acc[8];
#pragma unroll
        for (int i = 0; i < 8; ++i) acc[i] = bo[e0 + i];
#pragma unroll 8
        for (int d = 0; d < 64; ++d) {
            const float xv = atile[d * 65 + n];
#pragma unroll
            for (int i = 0; i < 8; ++i) acc[i] += wo[(e0 + i) * 64 + d] * xv;
        }
#pragma unroll
        for (int i = 0; i < 8; ++i)
            out[((size_t)(b * 64 + e0 + i) << 12) + n0 + n] = acc[i];
    }
}

// ---------------------------------------------------------------------------
extern "C" void kernel_launch(void* const* d_in, const int* in_sizes, int n_in,
                              void* d_out, int out_size, void* d_ws, size_t ws_size,
                              hipStream_t stream) {
    const float* x   = (const float*)d_in[0];
    const float* gnw = (const float*)d_in[1];
    const float* gnb = (const float*)d_in[2];
    const float* wq  = (const float*)d_in[3];
    const float* bq  = (const float*)d_in[4];
    const float* wk  = (const float*)d_in[5];
    const float* bk  = (const float*)d_in[6];
    const float* wv  = (const float*)d_in[7];
    const float* bv  = (const float*)d_in[8];
    const float* wo  = (const float*)d_in[9];
    const float* bo  = (const float*)d_in[10];
    float* out = (float*)d_out;

    char* wsb = (char*)d_ws;
    float*          stats = (float*)wsb;                                  //   2 KB
    unsigned short* Qt    = (unsigned short*)(wsb + 2048);                //   2 MB
    unsigned short* Kf    = (unsigned short*)(wsb + 2048 + 2097152);      //   2 MB
    unsigned short* Vf    = (unsigned short*)(wsb + 2048 + 2 * 2097152);  //   2 MB

    gn_stats_kernel<<<dim3(B_ * C_), dim3(1024), 0, stream>>>(x, stats);
    gn_qkv_kernel<<<dim3(B_ * 64), dim3(512), 0, stream>>>(
        x, stats, gnw, gnb, wq, bq, wk, bk, wv, bv, Qt, Kf, Vf);
    attn_kernel<<<dim3(B_ * 64), dim3(512), 0, stream>>>(
        Qt, Kf, Vf, wo, bo, out);
}